// Round 23
// baseline (67.601 us; speedup 1.0000x reference)
//
#include <hip/hip_runtime.h>

#define CLP_NATOMS 8192
#define CLP_NSHIFT 14
#define CLP_NROWS (CLP_NSHIFT * CLP_NATOMS)  // 114688 rows = (k, i)
#define CLP_NTILE 112                        // tiles of 1024 rows
#define CLP_NCELL 512                        // 8x8x8 spatial bins
#define CLP_CAP 128                          // max hits per row (k=0 max ~90)
#define CLP_PWAVES 2048                      // persistent waves (256 blk x 8)
#define CLP_C2 ((float)(5.2 * 5.2))          // f32 compare (JAX weak promotion)
#define CLP_R 5.35f                          // candidate interval half-width

__device__ const int clp_shifts[CLP_NSHIFT][3] = {
    {0, 0, 0},
    {-1, 0, 0}, {-1, -1, 0}, {0, -1, 0}, {1, -1, 0},
    {-1, 1, -1}, {0, 1, -1}, {1, 1, -1}, {-1, 0, -1},
    {0, 0, -1}, {1, 0, -1}, {-1, -1, -1}, {0, -1, -1}, {1, -1, -1}};

// Module-owned scratch (d_ws unused). Everything read is rewritten each call.
__device__ float4 clp_pp[CLP_NATOMS];      // wrapped coords
__device__ int clp_cid[CLP_NATOMS];        // cell id per atom
__device__ float4 clp_sorted[CLP_NATOMS];  // bin-sorted coords, .w = original i
__device__ unsigned clp_cstart[CLP_NCELL + 1];
__device__ unsigned clp_cfill0[CLP_NCELL]; // zero-based scatter counters
__device__ unsigned clp_nalive;            // alive-row count
__device__ unsigned clp_alist[CLP_NROWS];  // alive row ids (k<<13 | i)
__device__ int clp_jbuf[(size_t)CLP_NROWS * CLP_CAP];  // per-row sorted hit j's
__device__ unsigned clp_cnt[CLP_NROWS];
__device__ unsigned clp_off[CLP_NROWS];    // exclusive offset WITHIN tile
__device__ unsigned clp_tot[CLP_NTILE];    // per-tile totals (s1 writes)
__device__ float4 clp_dg;                  // cell diagonal
__device__ float4 clp_cinv;                // 8/diag per axis
__device__ float4 clp_sf[CLP_NSHIFT];      // s * diag (f32, __fmul_rn)

// Slab prune: d2<=c2 forces shifted atom i into a cutoff-wide boundary slab.
__device__ __forceinline__ bool clp_alive_f(float xi, float yi, float zi, int sx,
                                            int sy, int sz, float dgx, float dgy,
                                            float dgz) {
  bool a = true;
  if (sx < 0) a = a && (xi >= dgx - 5.3f); else if (sx > 0) a = a && (xi <= 5.3f);
  if (sy < 0) a = a && (yi >= dgy - 5.3f); else if (sy > 0) a = a && (yi <= 5.3f);
  if (sz < 0) a = a && (zi >= dgz - 5.3f); else if (sz > 0) a = a && (zi <= 5.3f);
  return a;
}

// Candidate cell range on one axis (monotone-rounding safe, 0.14 slack).
__device__ __forceinline__ void clp_crange(float t, float ci, int& lo, int& hi) {
  lo = max(0, (int)(fmaxf(t - CLP_R, 0.f) * ci));
  hi = min(7, (int)(fmaxf(t + CLP_R, 0.f) * ci));
}

__device__ __forceinline__ unsigned clp_iscan(unsigned v, int lane) {
  for (int off = 1; off < 64; off <<= 1) {
    unsigned t = __shfl_up(v, off);
    if (lane >= off) v += t;
  }
  return v;
}

// --- L1: wrap + cell-id; zero cnt/cfill0/nalive; publish constants ----------
// frac = x @ inv(cell); frac -= floor(frac); w = frac @ cell   (f32 per-op RN)
__global__ __launch_bounds__(512) void clp_wrapbin(const float* __restrict__ coords,
                                                   const float* __restrict__ cell) {
  int i = blockIdx.x * blockDim.x + threadIdx.x;
  if (i >= CLP_NATOMS) return;
  if (i < CLP_NCELL) clp_cfill0[i] = 0u;
  if (i == 0) clp_nalive = 0u;
#pragma unroll
  for (int k = 0; k < CLP_NSHIFT; ++k) clp_cnt[(k << 13) + i] = 0u;  // coalesced

  float dgx = (float)sqrt((double)cell[0] * cell[0] + (double)cell[3] * cell[3] +
                          (double)cell[6] * cell[6]);
  float dgy = (float)sqrt((double)cell[1] * cell[1] + (double)cell[4] * cell[4] +
                          (double)cell[7] * cell[7]);
  float dgz = (float)sqrt((double)cell[2] * cell[2] + (double)cell[5] * cell[5] +
                          (double)cell[8] * cell[8]);
  float cix = 8.0f / dgx, ciy = 8.0f / dgy, ciz = 8.0f / dgz;
  if (i == 0) {
    clp_dg = make_float4(dgx, dgy, dgz, 0.f);
    clp_cinv = make_float4(cix, ciy, ciz, 0.f);
    for (int k = 0; k < CLP_NSHIFT; ++k)
      clp_sf[k] = make_float4(__fmul_rn((float)clp_shifts[k][0], dgx),
                              __fmul_rn((float)clp_shifts[k][1], dgy),
                              __fmul_rn((float)clp_shifts[k][2], dgz), 0.f);
  }

  double a00 = cell[0], a01 = cell[1], a02 = cell[2];
  double a10 = cell[3], a11 = cell[4], a12 = cell[5];
  double a20 = cell[6], a21 = cell[7], a22 = cell[8];
  double det = a00 * (a11 * a22 - a12 * a21) - a01 * (a10 * a22 - a12 * a20) +
               a02 * (a10 * a21 - a11 * a20);
  double id = 1.0 / det;
  float inv[3][3];
  inv[0][0] = (float)((a11 * a22 - a12 * a21) * id);
  inv[0][1] = (float)(-(a01 * a22 - a02 * a21) * id);
  inv[0][2] = (float)((a01 * a12 - a02 * a11) * id);
  inv[1][0] = (float)(-(a10 * a22 - a12 * a20) * id);
  inv[1][1] = (float)((a00 * a22 - a02 * a20) * id);
  inv[1][2] = (float)(-(a00 * a12 - a02 * a10) * id);
  inv[2][0] = (float)((a10 * a21 - a11 * a20) * id);
  inv[2][1] = (float)(-(a00 * a21 - a01 * a20) * id);
  inv[2][2] = (float)((a00 * a11 - a01 * a10) * id);

  float x = coords[3 * i], y = coords[3 * i + 1], z = coords[3 * i + 2];
  float fr[3], w[3];
#pragma unroll
  for (int c = 0; c < 3; ++c) {
    float f = __fadd_rn(__fadd_rn(__fmul_rn(x, inv[0][c]), __fmul_rn(y, inv[1][c])),
                        __fmul_rn(z, inv[2][c]));
    fr[c] = __fsub_rn(f, floorf(f));
  }
#pragma unroll
  for (int c = 0; c < 3; ++c) {
    w[c] = __fadd_rn(
        __fadd_rn(__fmul_rn(fr[0], cell[0 * 3 + c]), __fmul_rn(fr[1], cell[1 * 3 + c])),
        __fmul_rn(fr[2], cell[2 * 3 + c]));
  }
  clp_pp[i] = make_float4(w[0], w[1], w[2], 0.0f);
  int cx = min(7, (int)(w[0] * cix));
  int cy = min(7, (int)(w[1] * ciy));
  int cz = min(7, (int)(w[2] * ciz));
  clp_cid[i] = (cz * 8 + cy) * 8 + cx;  // x fastest -> contiguous x-runs
}

// --- L2: scatter: 16 blocks x 512. Each block REDUNDANTLY builds the 512-bin
// histogram from cid in LDS + scans it (deterministic, identical in every
// block, no cross-block dependency/spin); block 0 publishes cstart. Then each
// block scatters its 512 atoms via zero-based cfill0 atomics and builds the
// alive-row list. (intra-cell order and alist order nondeterministic; both
// output-invariant: hits keyed by original index, rows own their slots) ------
__global__ __launch_bounds__(512) void clp_scatter() {
  __shared__ unsigned h[CLP_NCELL];
  __shared__ unsigned sc[CLP_NCELL];
  int tid = threadIdx.x;
  h[tid] = 0u;
  __syncthreads();
#pragma unroll
  for (int r = 0; r < 16; ++r) atomicAdd(&h[clp_cid[tid + r * 512]], 1u);
  __syncthreads();
  unsigned v = h[tid];
  unsigned acc = v;
  for (int off = 1; off < CLP_NCELL; off <<= 1) {
    unsigned a = (tid >= off) ? h[tid - off] : 0u;
    __syncthreads();
    acc += a;
    h[tid] = acc;
    __syncthreads();
  }
  sc[tid] = acc - v;  // exclusive cell start
  if (blockIdx.x == 0) {
    clp_cstart[tid] = acc - v;
    if (tid == CLP_NCELL - 1) clp_cstart[CLP_NCELL] = acc;
  }
  __syncthreads();

  int i = blockIdx.x * 512 + tid;
  float4 p = clp_pp[i];
  int c = clp_cid[i];
  unsigned pos = sc[c] + atomicAdd(&clp_cfill0[c], 1u);
  float4 ps = p;
  ps.w = __int_as_float(i);
  clp_sorted[pos] = ps;

  // alive (k,i) row list
  float4 dg = clp_dg;
  unsigned rows[CLP_NSHIFT];
  int m = 0;
  rows[m++] = (unsigned)i;  // k = 0 always alive
#pragma unroll
  for (int k = 1; k < CLP_NSHIFT; ++k) {
    if (clp_alive_f(p.x, p.y, p.z, clp_shifts[k][0], clp_shifts[k][1],
                    clp_shifts[k][2], dg.x, dg.y, dg.z))
      rows[m++] = (unsigned)((k << 13) + i);
  }
  unsigned base = atomicAdd(&clp_nalive, (unsigned)m);
  for (int q = 0; q < m; ++q) clp_alist[base + q] = rows[q];
}

// --- L3: count: persistent waves (256 blocks) over ALIVE rows; per row:
// cell-list candidates -> LDS bitmask -> sorted compact j-list + count.
// No atomics/fences beyond the LDS drain; skip test is wave-uniform from the
// reconverged mask (round-14 lesson). ---------------------------------------
__global__ __launch_bounds__(512) void clp_count() {
  __shared__ uint4 smask[8][64];  // 1KB mask per wave
  int wslot = threadIdx.x >> 6;
  int lane = threadIdx.x & 63;
  unsigned* lm = (unsigned*)smask[wslot];
  unsigned na = clp_nalive;
  float4 cinv = clp_cinv;

  for (unsigned w = blockIdx.x * 8 + wslot; w < na; w += CLP_PWAVES) {
    unsigned row = clp_alist[w];
    int k = row >> 13, i = row & (CLP_NATOMS - 1);
    float4 sc = clp_sf[k];
    float4 pi = clp_pp[i];
    smask[wslot][lane] = make_uint4(0u, 0u, 0u, 0u);

    int xlo, xhi, ylo, yhi, zlo, zhi;
    clp_crange(__fadd_rn(pi.x, sc.x), cinv.x, xlo, xhi);
    clp_crange(__fadd_rn(pi.y, sc.y), cinv.y, ylo, yhi);
    clp_crange(__fadd_rn(pi.z, sc.z), cinv.z, zlo, zhi);

    for (int cz = zlo; cz <= zhi; ++cz) {
      for (int cy = ylo; cy <= yhi; ++cy) {
        int idb = (cz * 8 + cy) * 8;
        unsigned b = clp_cstart[idb + xlo], e = clp_cstart[idb + xhi + 1];
        for (unsigned t = b + lane; t < e; t += 64) {
          float4 pj = clp_sorted[t];
          int j = __float_as_int(pj.w);
          float dx = __fadd_rn(__fsub_rn(pi.x, pj.x), sc.x);
          float dy = __fadd_rn(__fsub_rn(pi.y, pj.y), sc.y);
          float dz = __fadd_rn(__fsub_rn(pi.z, pj.z), sc.z);
          float d2 = __fadd_rn(__fadd_rn(__fmul_rn(dx, dx), __fmul_rn(dy, dy)),
                               __fmul_rn(dz, dz));
          bool ok = (d2 <= CLP_C2) && (k != 0 || i < j);
          if (ok) atomicOr(&lm[(unsigned)j >> 5], 1u << (j & 31));
        }
      }
    }
    __threadfence_block();  // drain LDS atomics; all lanes reconverged here

    const unsigned long long* mrow = (const unsigned long long*)lm;
    unsigned long long m0 = mrow[lane];       // j in [64*lane, 64*lane+64)
    unsigned long long m1 = mrow[64 + lane];  // j in [4096+64*lane, ...)
    if (__ballot((m0 | m1) != 0ull) == 0ull) continue;  // wave-uniform skip

    unsigned c0 = (unsigned)__popcll(m0), c1 = (unsigned)__popcll(m1);
    unsigned s0 = clp_iscan(c0, lane);
    unsigned T0 = __shfl(s0, 63);
    unsigned e0 = s0 - c0;
    unsigned s1 = clp_iscan(c1, lane);
    unsigned T1 = __shfl(s1, 63);
    unsigned e1 = T0 + s1 - c1;

    size_t jb = (size_t)row * CLP_CAP;
    unsigned p = e0;
    unsigned long long m = m0;
    while (m) {
      int b = __ffsll((long long)m) - 1;
      m &= m - 1;
      if (p < CLP_CAP) clp_jbuf[jb + p] = (lane << 6) + b;
      ++p;
    }
    p = e1;
    m = m1;
    while (m) {
      int b = __ffsll((long long)m) - 1;
      m &= m - 1;
      if (p < CLP_CAP) clp_jbuf[jb + p] = ((64 + lane) << 6) + b;
      ++p;
    }
    if (lane == 0) clp_cnt[row] = min(T0 + T1, (unsigned)CLP_CAP);
  }
}

// --- L4: per-1024-row tile exclusive scan + tile total ----------------------
__global__ __launch_bounds__(1024) void clp_s1() {
  __shared__ unsigned sd[1024];
  int t = threadIdx.x;
  int gid = blockIdx.x * 1024 + t;
  unsigned v = clp_cnt[gid];
  sd[t] = v;
  __syncthreads();
  unsigned acc = v;
  for (int off = 1; off < 1024; off <<= 1) {
    unsigned a = (t >= off) ? sd[t - off] : 0u;
    __syncthreads();
    acc += a;
    sd[t] = acc;
    __syncthreads();
  }
  clp_off[gid] = acc - v;
  if (t == 1023) clp_tot[blockIdx.x] = acc;
}

// --- L5: emit: persistent waves (256 blocks) over alive rows; per row: reduce
// preceding tile totals (<=112, L2-hot) inline for the base, then lanes copy
// the compact j-list into [ i xP | j xP | (sx,sy,sz) xP ] coalesced ----------
__global__ __launch_bounds__(512) void clp_emit(int* __restrict__ out, int P) {
  int wslot = threadIdx.x >> 6;
  int lane = threadIdx.x & 63;
  unsigned na = clp_nalive;

  for (unsigned w = blockIdx.x * 8 + wslot; w < na; w += CLP_PWAVES) {
    unsigned row = clp_alist[w];
    unsigned c = clp_cnt[row];  // wave-uniform load
    if (c == 0) continue;       // uniform branch
    int tile = row >> 10;       // 1024 rows per tile
    unsigned v = 0;
    if (lane < tile) v = clp_tot[lane];
    if (64 + lane < tile) v += clp_tot[64 + lane];
#pragma unroll
    for (int off = 32; off; off >>= 1) v += __shfl_down(v, off);
    unsigned tbase = __shfl(v, 0);

    unsigned off0 = clp_off[row] + tbase;
    int k = row >> 13, i = row & (CLP_NATOMS - 1);
    int sx = clp_shifts[k][0], sy = clp_shifts[k][1], sz = clp_shifts[k][2];
    size_t jb = (size_t)row * CLP_CAP;
    for (unsigned q = lane; q < c; q += 64) {
      unsigned p = off0 + q;
      if (p < (unsigned)P) {
        out[p] = i;
        out[P + p] = clp_jbuf[jb + q];
        unsigned sp = 2u * (unsigned)P + 3u * p;
        out[sp] = sx;
        out[sp + 1] = sy;
        out[sp + 2] = sz;
      }
    }
  }
}

extern "C" void kernel_launch(void* const* d_in, const int* in_sizes, int n_in,
                              void* d_out, int out_size, void* d_ws, size_t ws_size,
                              hipStream_t stream) {
  const float* coords = (const float*)d_in[1];  // (1, N, 3) f32
  const float* cell = (const float*)d_in[2];    // (3, 3) f32
  int P = out_size / 5;

  clp_wrapbin<<<CLP_NATOMS / 512, 512, 0, stream>>>(coords, cell);
  clp_scatter<<<16, 512, 0, stream>>>();
  clp_count<<<CLP_PWAVES / 8, 512, 0, stream>>>();
  clp_s1<<<CLP_NTILE, 1024, 0, stream>>>();
  clp_emit<<<CLP_PWAVES / 8, 512, 0, stream>>>((int*)d_out, P);
}